// Round 2
// baseline (5646.339 us; speedup 1.0000x reference)
//
#include <hip/hip_runtime.h>
#include <hip/hip_bf16.h>

typedef __bf16 bf16x8 __attribute__((ext_vector_type(8)));
typedef float  f32x4  __attribute__((ext_vector_type(4)));

#define PADK 40   // 32 k-elements + 8 pad (80B row stride -> bank-quad spread)
#define DELTA 5e-5f

// ---------------- weight prep: fold BN scale, split bf16, swizzle --------------
// conv1: 3 splits (hi/mid/lo), conv2: 2 splits. Layout per conv:
//   wp[split][kc][cout][32], k = r*128+cin, kc=k>>5, split stride 147456.
__global__ void prep_kernel(const float* __restrict__ w1, const float* __restrict__ g1,
                            const float* __restrict__ b1, const float* __restrict__ m1,
                            const float* __restrict__ v1,
                            const float* __restrict__ w2, const float* __restrict__ g2,
                            const float* __restrict__ b2, const float* __restrict__ m2,
                            const float* __restrict__ v2,
                            __bf16* __restrict__ wp, float* __restrict__ off)
{
    int idx  = blockIdx.x * 256 + threadIdx.x;     // 0 .. 294911
    int conv = idx / 147456;
    int rem  = idx - conv * 147456;
    int cout = rem / 1152;
    int k    = rem - cout * 1152;                  // k = r*128 + cin
    int r    = k >> 7;
    int cin  = k & 127;
    const float* w  = conv ? w2 : w1;
    const float* g  = conv ? g2 : g1;
    const float* vr = conv ? v2 : v1;
    float inv = g[cout] / sqrtf(vr[cout] + 1e-5f);
    float wv  = w[(cout * 128 + cin) * 9 + r] * inv;
    int kc = k >> 5, kk = k & 31;
    size_t pos = ((size_t)kc * 128 + cout) * 32 + kk;
    if (conv == 0) {
        __bf16 s0 = (__bf16)wv;
        float r1 = wv - (float)s0;
        __bf16 s1 = (__bf16)r1;
        __bf16 s2 = (__bf16)(r1 - (float)s1);
        wp[pos]              = s0;
        wp[147456 + pos]     = s1;
        wp[294912 + pos]     = s2;
    } else {
        __bf16 hi = (__bf16)wv;
        __bf16 lo = (__bf16)(wv - (float)hi);
        wp[442368 + pos]          = hi;
        wp[442368 + 147456 + pos] = lo;
    }
    if (idx < 256) {
        int cv = idx >> 7, co = idx & 127;
        const float* gg = cv ? g2 : g1;
        const float* bb = cv ? b2 : b1;
        const float* mm = cv ? m2 : m1;
        const float* vx = cv ? v2 : v1;
        float iv = gg[co] / sqrtf(vx[co] + 1e-5f);
        off[cv * 128 + co] = bb[co] - mm[co] * iv;
    }
}

// ---------------- IF neuron #1: x [T,B,C,H,W] f32 -> spikes NHWC bf16 ----------
// fp64 membrane: bit-matches an fp64 reference's spike decisions.
__global__ void if1_kernel(const float* __restrict__ x, __bf16* __restrict__ s1)
{
    const int blk = blockIdx.x;        // 1024 = B*H
    const int b   = blk >> 5;
    const int h   = blk & 31;
    const int tid = threadIdx.x;
    const int w   = tid & 31;
    const int g   = tid >> 5;          // 8 groups of 16 channels
    double v[16];
#pragma unroll
    for (int i = 0; i < 16; ++i) v[i] = 0.0;
    for (int t = 0; t < 8; ++t) {
        const size_t xbase = ((((size_t)t * 32 + b) * 128 + g * 16) * 32 + h) * 32 + w;
        unsigned short sp[16];
#pragma unroll
        for (int i = 0; i < 16; ++i) {
            v[i] += (double)x[xbase + (size_t)i * 1024];
            const bool s = (v[i] >= 1.0);
            sp[i] = s ? 0x3F80u : 0u;   // bf16 1.0 / 0.0
            if (s) v[i] = 0.0;
        }
        const size_t obase = (((size_t)(t * 32 + b) * 1024 + h * 32 + w) * 128 + g * 16);
        *(int4*)((unsigned short*)s1 + obase)     = *(const int4*)&sp[0];
        *(int4*)((unsigned short*)s1 + obase + 8) = *(const int4*)&sp[8];
    }
}

// ---------------- fp64 recompute of one near-threshold IF#2 site ---------------
// Re-derives the 1152 input-neuron IF#1 spike trains from x (bit-identical fp64
// to if1_kernel), builds y1[t] as fp64 selection sums of w1, redoes the IF scan.
__device__ __noinline__ void redo_site(const float* __restrict__ x,
                                       const float* __restrict__ w1,
                                       const float* __restrict__ g1,
                                       const float* __restrict__ b1,
                                       const float* __restrict__ m1,
                                       const float* __restrict__ v1r,
                                       int b, int p, int c, __bf16* __restrict__ s2)
{
    const int h = p >> 5, w_ = p & 31;
    double ysum[8];
#pragma unroll
    for (int t = 0; t < 8; ++t) ysum[t] = 0.0;
    for (int tap = 0; tap < 9; ++tap) {
        const int hh = h + tap / 3 - 1;
        const int ww = w_ + tap - (tap / 3) * 3 - 1;
        if (hh < 0 || hh > 31 || ww < 0 || ww > 31) continue;
        const int pix = hh * 32 + ww;
        for (int cg = 0; cg < 128; cg += 8) {
            double wv[8], vv[8];
#pragma unroll
            for (int u = 0; u < 8; ++u) {
                wv[u] = (double)w1[(size_t)(c * 128 + cg + u) * 9 + tap];
                vv[u] = 0.0;
            }
            for (int t = 0; t < 8; ++t) {
                const size_t xb = ((size_t)(t * 32 + b) * 128) * 1024 + (size_t)pix;
#pragma unroll
                for (int u = 0; u < 8; ++u) {
                    vv[u] += (double)x[xb + (size_t)(cg + u) * 1024];
                    if (vv[u] >= 1.0) { ysum[t] += wv[u]; vv[u] = 0.0; }
                }
            }
        }
    }
    const double inv  = (double)g1[c] / sqrt((double)v1r[c] + 1e-5);
    const double offc = (double)b1[c] - (double)m1[c] * inv;
    double vv = 0.0;
#pragma unroll
    for (int t = 0; t < 8; ++t) {
        vv += ysum[t] * inv + offc;
        const bool s = (vv >= 1.0);
        ((unsigned short*)s2)[((size_t)(t * 32 + b) * 1024 + p) * 128 + c] = s ? 0x3F80u : 0u;
        if (s) vv = 0.0;
    }
}

// ---------------- IF neuron #2: y1 NHWC f32 -> spikes NHWC bf16 ---------------
// Flags sites whose membrane comes within DELTA of threshold; redoes those in fp64.
__global__ void if2_kernel(const float* __restrict__ y1, __bf16* __restrict__ s2,
                           const float* __restrict__ x, const float* __restrict__ w1,
                           const float* __restrict__ g1, const float* __restrict__ b1,
                           const float* __restrict__ m1, const float* __restrict__ v1r)
{
    const size_t idx = (size_t)blockIdx.x * 256 + threadIdx.x;  // 8.4M threads
    const int c4 = (int)(idx & 31);
    const int p  = (int)((idx >> 5) & 1023);
    const int b  = (int)(idx >> 15);
    float v[4];
    int flag = 0;
#pragma unroll
    for (int i = 0; i < 4; ++i) v[i] = 0.f;
    for (int t = 0; t < 8; ++t) {
        const size_t base = ((size_t)(t * 32 + b) * 1024 + p) * 128 + c4 * 4;
        const f32x4 xv = *(const f32x4*)&y1[base];
        unsigned short sp[4];
#pragma unroll
        for (int i = 0; i < 4; ++i) {
            v[i] += xv[i];
            const float d = v[i] - 1.0f;
            if (fabsf(d) < DELTA) flag |= (1 << i);
            const bool s = (d >= 0.0f);
            sp[i] = s ? 0x3F80u : 0u;
            if (s) v[i] = 0.f;
        }
        *(uint2*)((unsigned short*)s2 + base) = *(const uint2*)&sp[0];
    }
    if (flag) {
#pragma unroll 1
        for (int i = 0; i < 4; ++i)
            if ((flag >> i) & 1)
                redo_site(x, w1, g1, b1, m1, v1r, b, p, c4 * 4 + i, s2);
    }
}

// ---------------- conv3x3 (+folded BN) as implicit GEMM via MFMA --------------
// Block: 1 image (tb), 128-pixel strip x 128 couts. 4 waves, 64x64 each via
// 4x4 mfma_f32_16x16x32_bf16. K = 36 chunks of 32. NSPLIT weight halves.
template<int NSPLIT, bool OUT_NCHW>
__global__ __launch_bounds__(256, 3)
void conv_kernel(const __bf16* __restrict__ sin, const __bf16* __restrict__ wp,
                 const float* __restrict__ off, float* __restrict__ out)
{
    __shared__ __bf16 Ast[128 * PADK];
    __shared__ __bf16 Bst[NSPLIT * 128 * PADK];
    const int tid  = threadIdx.x;
    const int blk  = blockIdx.x;
    const int tb   = blk >> 3;        // image index (t*32+b)
    const int pblk = blk & 7;         // 128-pixel strip
    const int wave = tid >> 6;
    const int wm = wave >> 1, wn = wave & 1;
    const int lane15 = tid & 15;
    const int q = (tid >> 4) & 3;

    f32x4 acc[4][4];
#pragma unroll
    for (int i = 0; i < 4; ++i)
#pragma unroll
        for (int j = 0; j < 4; ++j)
#pragma unroll
            for (int rg = 0; rg < 4; ++rg) acc[i][j][rg] = 0.0f;

    const int p_l  = tid >> 1;        // staging: pixel / cout row 0..127
    const int half = tid & 1;         // 16-channel half
    const int y0 = (pblk << 2) + (p_l >> 5);
    const int x0 = p_l & 31;

    for (int kc = 0; kc < 36; ++kc) {
        const int r  = kc >> 2;           // tap 0..8
        const int ci = kc & 3;            // cin block of 32
        const int dy = r / 3 - 1;
        const int dx = r - (r / 3) * 3 - 1;
        const int yy = y0 + dy, xx = x0 + dx;
        int4 a0 = {0,0,0,0}, a1 = {0,0,0,0};
        if (yy >= 0 && yy < 32 && xx >= 0 && xx < 32) {
            const int4* src = (const int4*)(sin +
                (((size_t)tb * 1024 + (size_t)(yy * 32 + xx)) * 128 + ci * 32 + half * 16));
            a0 = src[0];
            a1 = src[1];
        }
        int4 breg[NSPLIT][2];
#pragma unroll
        for (int s = 0; s < NSPLIT; ++s) {
            const int4* ws = (const int4*)(wp + ((size_t)(s * 36 + kc) * 128 + p_l) * 32 + half * 16);
            breg[s][0] = ws[0];
            breg[s][1] = ws[1];
        }
        __syncthreads();   // previous iteration's LDS reads complete
        *(int4*)&Ast[p_l * PADK + half * 16]     = a0;
        *(int4*)&Ast[p_l * PADK + half * 16 + 8] = a1;
#pragma unroll
        for (int s = 0; s < NSPLIT; ++s) {
            *(int4*)&Bst[s * (128 * PADK) + p_l * PADK + half * 16]     = breg[s][0];
            *(int4*)&Bst[s * (128 * PADK) + p_l * PADK + half * 16 + 8] = breg[s][1];
        }
        __syncthreads();
        bf16x8 af[4];
#pragma unroll
        for (int i = 0; i < 4; ++i)
            af[i] = *(const bf16x8*)&Ast[(wm * 64 + i * 16 + lane15) * PADK + q * 8];
#pragma unroll
        for (int s = 0; s < NSPLIT; ++s) {
#pragma unroll
            for (int j = 0; j < 4; ++j) {
                bf16x8 bf = *(const bf16x8*)&Bst[s * (128 * PADK) + (wn * 64 + j * 16 + lane15) * PADK + q * 8];
#pragma unroll
                for (int i = 0; i < 4; ++i)
                    acc[i][j] = __builtin_amdgcn_mfma_f32_16x16x32_bf16(af[i], bf, acc[i][j], 0, 0, 0);
            }
        }
    }

    // epilogue: + BN offset, store (C/D map verified empirically in R1)
    float offv[4];
#pragma unroll
    for (int j = 0; j < 4; ++j) offv[j] = off[wn * 64 + j * 16 + lane15];
#pragma unroll
    for (int i = 0; i < 4; ++i) {
        const int prow = pblk * 128 + wm * 64 + i * 16 + q * 4;
#pragma unroll
        for (int j = 0; j < 4; ++j) {
            const int col = wn * 64 + j * 16 + lane15;
            if (OUT_NCHW) {
                f32x4 vv;
#pragma unroll
                for (int rg = 0; rg < 4; ++rg) vv[rg] = acc[i][j][rg] + offv[j];
                *(f32x4*)&out[(size_t)tb * 131072 + (size_t)col * 1024 + prow] = vv;
            } else {
#pragma unroll
                for (int rg = 0; rg < 4; ++rg)
                    out[((size_t)tb * 1024 + prow + rg) * 128 + col] = acc[i][j][rg] + offv[j];
            }
        }
    }
}

extern "C" void kernel_launch(void* const* d_in, const int* in_sizes, int n_in,
                              void* d_out, int out_size, void* d_ws, size_t ws_size,
                              hipStream_t stream)
{
    const float* x  = (const float*)d_in[0];
    const float* w1 = (const float*)d_in[1];
    const float* g1 = (const float*)d_in[2];
    const float* b1 = (const float*)d_in[3];
    const float* m1 = (const float*)d_in[4];
    const float* v1 = (const float*)d_in[5];
    const float* w2 = (const float*)d_in[6];
    const float* g2 = (const float*)d_in[7];
    const float* b2 = (const float*)d_in[8];
    const float* m2 = (const float*)d_in[9];
    const float* v2 = (const float*)d_in[10];
    float* out = (float*)d_out;

    // ws layout: spikes (bf16, s1 then s2 reuse) | y1 (f32) | weights | off
    char* ws = (char*)d_ws;
    __bf16* s_buf = (__bf16*)ws;                                       // 67,108,864 B
    float*  y1    = (float*)(ws + (size_t)67108864);                   // 134,217,728 B
    __bf16* wp    = (__bf16*)(ws + (size_t)67108864 + 134217728);      // 1,474,560 B
    float*  off   = (float*)(ws + (size_t)67108864 + 134217728 + 1474560);

    prep_kernel<<<1152, 256, 0, stream>>>(w1, g1, b1, m1, v1, w2, g2, b2, m2, v2, wp, off);
    if1_kernel<<<1024, 256, 0, stream>>>(x, s_buf);
    conv_kernel<3, false><<<2048, 256, 0, stream>>>(s_buf, wp, off, y1);
    if2_kernel<<<4096, 256, 0, stream>>>(y1, s_buf, x, w1, g1, b1, m1, v1);
    conv_kernel<2, true><<<2048, 256, 0, stream>>>(s_buf, wp + 442368, off + 128, out);
}

// Round 3
// 1335.225 us; speedup vs baseline: 4.2288x; 4.2288x over previous
//
#include <hip/hip_runtime.h>
#include <hip/hip_bf16.h>

typedef __bf16 bf16x8 __attribute__((ext_vector_type(8)));
typedef float  f32x4  __attribute__((ext_vector_type(4)));

#define PADK 40   // 32 k-elements + 8 pad (80B row stride -> bank-quad spread)
#define DELTA 5e-5f
#define LIST_CAP 4194304

// ---------------- weight prep: fold BN scale, split bf16, swizzle --------------
// conv1: 3 splits (hi/mid/lo), conv2: 2 splits. Layout per conv:
//   wp[split][kc][cout][32], k = r*128+cin, kc=k>>5, split stride 147456.
__global__ void prep_kernel(const float* __restrict__ w1, const float* __restrict__ g1,
                            const float* __restrict__ b1, const float* __restrict__ m1,
                            const float* __restrict__ v1,
                            const float* __restrict__ w2, const float* __restrict__ g2,
                            const float* __restrict__ b2, const float* __restrict__ m2,
                            const float* __restrict__ v2,
                            __bf16* __restrict__ wp, float* __restrict__ off,
                            int* __restrict__ cnt)
{
    int idx  = blockIdx.x * 256 + threadIdx.x;     // 0 .. 294911
    if (idx == 0) cnt[0] = 0;                      // ws is re-poisoned every launch
    int conv = idx / 147456;
    int rem  = idx - conv * 147456;
    int cout = rem / 1152;
    int k    = rem - cout * 1152;                  // k = r*128 + cin
    int r    = k >> 7;
    int cin  = k & 127;
    const float* w  = conv ? w2 : w1;
    const float* g  = conv ? g2 : g1;
    const float* vr = conv ? v2 : v1;
    float inv = g[cout] / sqrtf(vr[cout] + 1e-5f);
    float wv  = w[(cout * 128 + cin) * 9 + r] * inv;
    int kc = k >> 5, kk = k & 31;
    size_t pos = ((size_t)kc * 128 + cout) * 32 + kk;
    if (conv == 0) {
        __bf16 s0 = (__bf16)wv;
        float r1 = wv - (float)s0;
        __bf16 s1 = (__bf16)r1;
        __bf16 s2 = (__bf16)(r1 - (float)s1);
        wp[pos]              = s0;
        wp[147456 + pos]     = s1;
        wp[294912 + pos]     = s2;
    } else {
        __bf16 hi = (__bf16)wv;
        __bf16 lo = (__bf16)(wv - (float)hi);
        wp[442368 + pos]          = hi;
        wp[442368 + 147456 + pos] = lo;
    }
    if (idx < 256) {
        int cv = idx >> 7, co = idx & 127;
        const float* gg = cv ? g2 : g1;
        const float* bb = cv ? b2 : b1;
        const float* mm = cv ? m2 : m1;
        const float* vx = cv ? v2 : v1;
        float iv = gg[co] / sqrtf(vx[co] + 1e-5f);
        off[cv * 128 + co] = bb[co] - mm[co] * iv;
    }
}

// ---------------- IF neuron #1: x [T,B,C,H,W] f32 -> spikes NHWC bf16 ----------
// fp64 membrane: bit-matches an fp64 reference's spike decisions.
__global__ void if1_kernel(const float* __restrict__ x, __bf16* __restrict__ s1)
{
    const int blk = blockIdx.x;        // 1024 = B*H
    const int b   = blk >> 5;
    const int h   = blk & 31;
    const int tid = threadIdx.x;
    const int w   = tid & 31;
    const int g   = tid >> 5;          // 8 groups of 16 channels
    double v[16];
#pragma unroll
    for (int i = 0; i < 16; ++i) v[i] = 0.0;
    for (int t = 0; t < 8; ++t) {
        const size_t xbase = ((((size_t)t * 32 + b) * 128 + g * 16) * 32 + h) * 32 + w;
        unsigned short sp[16];
#pragma unroll
        for (int i = 0; i < 16; ++i) {
            v[i] += (double)x[xbase + (size_t)i * 1024];
            const bool s = (v[i] >= 1.0);
            sp[i] = s ? 0x3F80u : 0u;   // bf16 1.0 / 0.0
            if (s) v[i] = 0.0;
        }
        const size_t obase = (((size_t)(t * 32 + b) * 1024 + h * 32 + w) * 128 + g * 16);
        *(int4*)((unsigned short*)s1 + obase)     = *(const int4*)&sp[0];
        *(int4*)((unsigned short*)s1 + obase + 8) = *(const int4*)&sp[8];
    }
}

// ---------------- IF neuron #2 phase A: scan + flag near-threshold sites ------
__global__ void if2_kernel(const float* __restrict__ y1, __bf16* __restrict__ s2,
                           int* __restrict__ cnt, int* __restrict__ list)
{
    const size_t idx = (size_t)blockIdx.x * 256 + threadIdx.x;  // 1,048,576 threads
    const int c4 = (int)(idx & 31);
    const int p  = (int)((idx >> 5) & 1023);
    const int b  = (int)(idx >> 15);
    float v[4];
    int flag = 0;
#pragma unroll
    for (int i = 0; i < 4; ++i) v[i] = 0.f;
    for (int t = 0; t < 8; ++t) {
        const size_t base = ((size_t)(t * 32 + b) * 1024 + p) * 128 + c4 * 4;
        const f32x4 xv = *(const f32x4*)&y1[base];
        unsigned short sp[4];
#pragma unroll
        for (int i = 0; i < 4; ++i) {
            v[i] += xv[i];
            const float d = v[i] - 1.0f;
            if (fabsf(d) < DELTA) flag |= (1 << i);
            const bool s = (d >= 0.0f);
            sp[i] = s ? 0x3F80u : 0u;
            if (s) v[i] = 0.f;
        }
        *(uint2*)((unsigned short*)s2 + base) = *(const uint2*)&sp[0];
    }
    if (flag) {
#pragma unroll 1
        for (int i = 0; i < 4; ++i)
            if ((flag >> i) & 1) {
                const int pos = atomicAdd(cnt, 1);
                if (pos < LIST_CAP)
                    list[pos] = (b << 17) | (p << 7) | (c4 * 4 + i);
            }
    }
}

// ---------------- IF#2 phase B: fp64 redo, one 256-thread block per site ------
// Thread = (cin, tap-group). Recomputes IF#1 spike decisions from x in fp64
// (bit-identical to if1_kernel's scan), accumulates selection sums of w1,
// LDS tree-reduce, then single-thread fp64 IF scan overwrites the 8 spikes.
__global__ __launch_bounds__(256)
void redo_kernel(const float* __restrict__ x, const float* __restrict__ w1,
                 const float* __restrict__ g1, const float* __restrict__ b1,
                 const float* __restrict__ m1, const float* __restrict__ v1r,
                 const int* __restrict__ cnt, const int* __restrict__ list,
                 __bf16* __restrict__ s2)
{
    __shared__ double red[256][8];   // 16 KB
    const int count = min(cnt[0], LIST_CAP);
    const int tid = threadIdx.x;
    const int cin = tid & 127;
    const int tg  = tid >> 7;
    for (int i = blockIdx.x; i < count; i += gridDim.x) {
        const int pk = list[i];
        const int b = pk >> 17, p = (pk >> 7) & 1023, c = pk & 127;
        const int h = p >> 5, w_ = p & 31;
        double part[8];
#pragma unroll
        for (int t = 0; t < 8; ++t) part[t] = 0.0;
        const int tap0 = tg ? 5 : 0, tap1 = tg ? 9 : 5;
        for (int tap = tap0; tap < tap1; ++tap) {
            const int hh = h + tap / 3 - 1;
            const int ww = w_ + tap - (tap / 3) * 3 - 1;
            if (hh < 0 || hh > 31 || ww < 0 || ww > 31) continue;
            const int pix = hh * 32 + ww;
            const double wv = (double)w1[(size_t)(c * 128 + cin) * 9 + tap];
            double v = 0.0;
#pragma unroll
            for (int t = 0; t < 8; ++t) {
                v += (double)x[((size_t)(t * 32 + b) * 128 + cin) * 1024 + pix];
                if (v >= 1.0) { part[t] += wv; v = 0.0; }
            }
        }
#pragma unroll
        for (int t = 0; t < 8; ++t) red[tid][t] = part[t];
        __syncthreads();
        for (int s = 128; s > 0; s >>= 1) {
            if (tid < s)
#pragma unroll
                for (int t = 0; t < 8; ++t) red[tid][t] += red[tid + s][t];
            __syncthreads();
        }
        if (tid == 0) {
            const double inv  = (double)g1[c] / sqrt((double)v1r[c] + 1e-5);
            const double offc = (double)b1[c] - (double)m1[c] * inv;
            double v = 0.0;
#pragma unroll
            for (int t = 0; t < 8; ++t) {
                v += red[0][t] * inv + offc;
                const bool s = (v >= 1.0);
                ((unsigned short*)s2)[((size_t)(t * 32 + b) * 1024 + p) * 128 + c] = s ? 0x3F80u : 0u;
                if (s) v = 0.0;
            }
        }
        __syncthreads();   // LDS reused next site
    }
}

// ---------------- conv3x3 (+folded BN) as implicit GEMM via MFMA --------------
// Block: 1 image (tb), 128-pixel strip x 128 couts. 4 waves, 64x64 each via
// 4x4 mfma_f32_16x16x32_bf16. K = 36 chunks of 32. NSPLIT weight halves.
template<int NSPLIT, bool OUT_NCHW>
__global__ __launch_bounds__(256, 3)
void conv_kernel(const __bf16* __restrict__ sin, const __bf16* __restrict__ wp,
                 const float* __restrict__ off, float* __restrict__ out)
{
    __shared__ __bf16 Ast[128 * PADK];
    __shared__ __bf16 Bst[NSPLIT * 128 * PADK];
    const int tid  = threadIdx.x;
    const int blk  = blockIdx.x;
    const int tb   = blk >> 3;        // image index (t*32+b)
    const int pblk = blk & 7;         // 128-pixel strip
    const int wave = tid >> 6;
    const int wm = wave >> 1, wn = wave & 1;
    const int lane15 = tid & 15;
    const int q = (tid >> 4) & 3;

    f32x4 acc[4][4];
#pragma unroll
    for (int i = 0; i < 4; ++i)
#pragma unroll
        for (int j = 0; j < 4; ++j)
#pragma unroll
            for (int rg = 0; rg < 4; ++rg) acc[i][j][rg] = 0.0f;

    const int p_l  = tid >> 1;        // staging: pixel / cout row 0..127
    const int half = tid & 1;         // 16-channel half
    const int y0 = (pblk << 2) + (p_l >> 5);
    const int x0 = p_l & 31;

    for (int kc = 0; kc < 36; ++kc) {
        const int r  = kc >> 2;           // tap 0..8
        const int ci = kc & 3;            // cin block of 32
        const int dy = r / 3 - 1;
        const int dx = r - (r / 3) * 3 - 1;
        const int yy = y0 + dy, xx = x0 + dx;
        int4 a0 = {0,0,0,0}, a1 = {0,0,0,0};
        if (yy >= 0 && yy < 32 && xx >= 0 && xx < 32) {
            const int4* src = (const int4*)(sin +
                (((size_t)tb * 1024 + (size_t)(yy * 32 + xx)) * 128 + ci * 32 + half * 16));
            a0 = src[0];
            a1 = src[1];
        }
        int4 breg[NSPLIT][2];
#pragma unroll
        for (int s = 0; s < NSPLIT; ++s) {
            const int4* ws = (const int4*)(wp + ((size_t)(s * 36 + kc) * 128 + p_l) * 32 + half * 16);
            breg[s][0] = ws[0];
            breg[s][1] = ws[1];
        }
        __syncthreads();   // previous iteration's LDS reads complete
        *(int4*)&Ast[p_l * PADK + half * 16]     = a0;
        *(int4*)&Ast[p_l * PADK + half * 16 + 8] = a1;
#pragma unroll
        for (int s = 0; s < NSPLIT; ++s) {
            *(int4*)&Bst[s * (128 * PADK) + p_l * PADK + half * 16]     = breg[s][0];
            *(int4*)&Bst[s * (128 * PADK) + p_l * PADK + half * 16 + 8] = breg[s][1];
        }
        __syncthreads();
        bf16x8 af[4];
#pragma unroll
        for (int i = 0; i < 4; ++i)
            af[i] = *(const bf16x8*)&Ast[(wm * 64 + i * 16 + lane15) * PADK + q * 8];
#pragma unroll
        for (int s = 0; s < NSPLIT; ++s) {
#pragma unroll
            for (int j = 0; j < 4; ++j) {
                bf16x8 bf = *(const bf16x8*)&Bst[s * (128 * PADK) + (wn * 64 + j * 16 + lane15) * PADK + q * 8];
#pragma unroll
                for (int i = 0; i < 4; ++i)
                    acc[i][j] = __builtin_amdgcn_mfma_f32_16x16x32_bf16(af[i], bf, acc[i][j], 0, 0, 0);
            }
        }
    }

    // epilogue: + BN offset, store (C/D map: col=lane&15, row=quad*4+reg)
    float offv[4];
#pragma unroll
    for (int j = 0; j < 4; ++j) offv[j] = off[wn * 64 + j * 16 + lane15];
#pragma unroll
    for (int i = 0; i < 4; ++i) {
        const int prow = pblk * 128 + wm * 64 + i * 16 + q * 4;
#pragma unroll
        for (int j = 0; j < 4; ++j) {
            const int col = wn * 64 + j * 16 + lane15;
            if (OUT_NCHW) {
                f32x4 vv;
#pragma unroll
                for (int rg = 0; rg < 4; ++rg) vv[rg] = acc[i][j][rg] + offv[j];
                *(f32x4*)&out[(size_t)tb * 131072 + (size_t)col * 1024 + prow] = vv;
            } else {
#pragma unroll
                for (int rg = 0; rg < 4; ++rg)
                    out[((size_t)tb * 1024 + prow + rg) * 128 + col] = acc[i][j][rg] + offv[j];
            }
        }
    }
}

extern "C" void kernel_launch(void* const* d_in, const int* in_sizes, int n_in,
                              void* d_out, int out_size, void* d_ws, size_t ws_size,
                              hipStream_t stream)
{
    const float* x  = (const float*)d_in[0];
    const float* w1 = (const float*)d_in[1];
    const float* g1 = (const float*)d_in[2];
    const float* b1 = (const float*)d_in[3];
    const float* m1 = (const float*)d_in[4];
    const float* v1 = (const float*)d_in[5];
    const float* w2 = (const float*)d_in[6];
    const float* g2 = (const float*)d_in[7];
    const float* b2 = (const float*)d_in[8];
    const float* m2 = (const float*)d_in[9];
    const float* v2 = (const float*)d_in[10];
    float* out = (float*)d_out;

    // ws layout: spikes (bf16, s1 then s2 reuse) | y1 f32 | weights | off | cnt | list
    char* ws = (char*)d_ws;
    __bf16* s_buf = (__bf16*)ws;                                       // 67,108,864 B
    float*  y1    = (float*)(ws + (size_t)67108864);                   // 134,217,728 B
    __bf16* wp    = (__bf16*)(ws + (size_t)201326592);                 // 1,474,560 B
    float*  off   = (float*)(ws + (size_t)202801152);                  // 1,024 B
    int*    cnt   = (int*)  (ws + (size_t)202802176);                  // 4 B
    int*    list  = (int*)  (ws + (size_t)202802180);                  // 16 MB cap

    prep_kernel<<<1152, 256, 0, stream>>>(w1, g1, b1, m1, v1, w2, g2, b2, m2, v2, wp, off, cnt);
    if1_kernel<<<1024, 256, 0, stream>>>(x, s_buf);
    conv_kernel<3, false><<<2048, 256, 0, stream>>>(s_buf, wp, off, y1);
    if2_kernel<<<4096, 256, 0, stream>>>(y1, s_buf, cnt, list);
    redo_kernel<<<2048, 256, 0, stream>>>(x, w1, g1, b1, m1, v1, cnt, list, s_buf);
    conv_kernel<2, true><<<2048, 256, 0, stream>>>(s_buf, wp + 442368, off + 128, out);
}

// Round 4
// 960.401 us; speedup vs baseline: 5.8791x; 1.3903x over previous
//
#include <hip/hip_runtime.h>
#include <hip/hip_bf16.h>

typedef __bf16 bf16x8 __attribute__((ext_vector_type(8)));
typedef float  f32x4  __attribute__((ext_vector_type(4)));

#define DELTA 5e-5f
#define LIST_CAP 4194304

// ---------------- weight prep: fold BN scale, split bf16, swizzle --------------
// conv1: 3 splits (hi/mid/lo), conv2: 2 splits. Layout per conv:
//   wp[split][kc][cout][32], k = r*128+cin, kc=k>>5, split stride 147456.
__global__ void prep_kernel(const float* __restrict__ w1, const float* __restrict__ g1,
                            const float* __restrict__ b1, const float* __restrict__ m1,
                            const float* __restrict__ v1,
                            const float* __restrict__ w2, const float* __restrict__ g2,
                            const float* __restrict__ b2, const float* __restrict__ m2,
                            const float* __restrict__ v2,
                            __bf16* __restrict__ wp, float* __restrict__ off,
                            int* __restrict__ cnt)
{
    int idx  = blockIdx.x * 256 + threadIdx.x;     // 0 .. 294911
    if (idx == 0) cnt[0] = 0;                      // ws is re-poisoned every launch
    int conv = idx / 147456;
    int rem  = idx - conv * 147456;
    int cout = rem / 1152;
    int k    = rem - cout * 1152;                  // k = r*128 + cin
    int r    = k >> 7;
    int cin  = k & 127;
    const float* w  = conv ? w2 : w1;
    const float* g  = conv ? g2 : g1;
    const float* vr = conv ? v2 : v1;
    float inv = g[cout] / sqrtf(vr[cout] + 1e-5f);
    float wv  = w[(cout * 128 + cin) * 9 + r] * inv;
    int kc = k >> 5, kk = k & 31;
    size_t pos = ((size_t)kc * 128 + cout) * 32 + kk;
    if (conv == 0) {
        __bf16 s0 = (__bf16)wv;
        float r1 = wv - (float)s0;
        __bf16 s1 = (__bf16)r1;
        __bf16 s2 = (__bf16)(r1 - (float)s1);
        wp[pos]              = s0;
        wp[147456 + pos]     = s1;
        wp[294912 + pos]     = s2;
    } else {
        __bf16 hi = (__bf16)wv;
        __bf16 lo = (__bf16)(wv - (float)hi);
        wp[442368 + pos]          = hi;
        wp[442368 + 147456 + pos] = lo;
    }
    if (idx < 256) {
        int cv = idx >> 7, co = idx & 127;
        const float* gg = cv ? g2 : g1;
        const float* bb = cv ? b2 : b1;
        const float* mm = cv ? m2 : m1;
        const float* vx = cv ? v2 : v1;
        float iv = gg[co] / sqrtf(vx[co] + 1e-5f);
        off[cv * 128 + co] = bb[co] - mm[co] * iv;
    }
}

// ---------------- IF neuron #1: x [T,B,C,H,W] f32 -> spikes NHWC bf16 ----------
// fp64 membrane: bit-matches an fp64 reference's spike decisions.
__global__ void if1_kernel(const float* __restrict__ x, __bf16* __restrict__ s1)
{
    const int blk = blockIdx.x;        // 1024 = B*H
    const int b   = blk >> 5;
    const int h   = blk & 31;
    const int tid = threadIdx.x;
    const int w   = tid & 31;
    const int g   = tid >> 5;          // 8 groups of 16 channels
    double v[16];
#pragma unroll
    for (int i = 0; i < 16; ++i) v[i] = 0.0;
    for (int t = 0; t < 8; ++t) {
        const size_t xbase = ((((size_t)t * 32 + b) * 128 + g * 16) * 32 + h) * 32 + w;
        unsigned short sp[16];
#pragma unroll
        for (int i = 0; i < 16; ++i) {
            v[i] += (double)x[xbase + (size_t)i * 1024];
            const bool s = (v[i] >= 1.0);
            sp[i] = s ? 0x3F80u : 0u;   // bf16 1.0 / 0.0
            if (s) v[i] = 0.0;
        }
        const size_t obase = (((size_t)(t * 32 + b) * 1024 + h * 32 + w) * 128 + g * 16);
        *(int4*)((unsigned short*)s1 + obase)     = *(const int4*)&sp[0];
        *(int4*)((unsigned short*)s1 + obase + 8) = *(const int4*)&sp[8];
    }
}

// ---------------- IF neuron #2 phase A: scan + flag near-threshold sites ------
__global__ void if2_kernel(const float* __restrict__ y1, __bf16* __restrict__ s2,
                           int* __restrict__ cnt, int* __restrict__ list)
{
    const size_t idx = (size_t)blockIdx.x * 256 + threadIdx.x;  // 1,048,576 threads
    const int c4 = (int)(idx & 31);
    const int p  = (int)((idx >> 5) & 1023);
    const int b  = (int)(idx >> 15);
    float v[4];
    int flag = 0;
#pragma unroll
    for (int i = 0; i < 4; ++i) v[i] = 0.f;
    for (int t = 0; t < 8; ++t) {
        const size_t base = ((size_t)(t * 32 + b) * 1024 + p) * 128 + c4 * 4;
        const f32x4 xv = *(const f32x4*)&y1[base];
        unsigned short sp[4];
#pragma unroll
        for (int i = 0; i < 4; ++i) {
            v[i] += xv[i];
            const float d = v[i] - 1.0f;
            if (fabsf(d) < DELTA) flag |= (1 << i);
            const bool s = (d >= 0.0f);
            sp[i] = s ? 0x3F80u : 0u;
            if (s) v[i] = 0.f;
        }
        *(uint2*)((unsigned short*)s2 + base) = *(const uint2*)&sp[0];
    }
    if (flag) {
#pragma unroll 1
        for (int i = 0; i < 4; ++i)
            if ((flag >> i) & 1) {
                const int pos = atomicAdd(cnt, 1);
                if (pos < LIST_CAP)
                    list[pos] = (b << 17) | (p << 7) | (c4 * 4 + i);
            }
    }
}

// ---------------- IF#2 phase B: fp64 redo, one 256-thread block per site ------
__global__ __launch_bounds__(256)
void redo_kernel(const float* __restrict__ x, const float* __restrict__ w1,
                 const float* __restrict__ g1, const float* __restrict__ b1,
                 const float* __restrict__ m1, const float* __restrict__ v1r,
                 const int* __restrict__ cnt, const int* __restrict__ list,
                 __bf16* __restrict__ s2)
{
    __shared__ double red[256][8];   // 16 KB
    const int count = min(cnt[0], LIST_CAP);
    const int tid = threadIdx.x;
    const int cin = tid & 127;
    const int tg  = tid >> 7;
    for (int i = blockIdx.x; i < count; i += gridDim.x) {
        const int pk = list[i];
        const int b = pk >> 17, p = (pk >> 7) & 1023, c = pk & 127;
        const int h = p >> 5, w_ = p & 31;
        double part[8];
#pragma unroll
        for (int t = 0; t < 8; ++t) part[t] = 0.0;
        const int tap0 = tg ? 5 : 0, tap1 = tg ? 9 : 5;
        for (int tap = tap0; tap < tap1; ++tap) {
            const int hh = h + tap / 3 - 1;
            const int ww = w_ + tap - (tap / 3) * 3 - 1;
            if (hh < 0 || hh > 31 || ww < 0 || ww > 31) continue;
            const int pix = hh * 32 + ww;
            const double wv = (double)w1[(size_t)(c * 128 + cin) * 9 + tap];
            double v = 0.0;
#pragma unroll
            for (int t = 0; t < 8; ++t) {
                v += (double)x[((size_t)(t * 32 + b) * 128 + cin) * 1024 + pix];
                if (v >= 1.0) { part[t] += wv; v = 0.0; }
            }
        }
#pragma unroll
        for (int t = 0; t < 8; ++t) red[tid][t] = part[t];
        __syncthreads();
        for (int s = 128; s > 0; s >>= 1) {
            if (tid < s)
#pragma unroll
                for (int t = 0; t < 8; ++t) red[tid][t] += red[tid + s][t];
            __syncthreads();
        }
        if (tid == 0) {
            const double inv  = (double)g1[c] / sqrt((double)v1r[c] + 1e-5);
            const double offc = (double)b1[c] - (double)m1[c] * inv;
            double v = 0.0;
#pragma unroll
            for (int t = 0; t < 8; ++t) {
                v += red[0][t] * inv + offc;
                const bool s = (v >= 1.0);
                ((unsigned short*)s2)[((size_t)(t * 32 + b) * 1024 + p) * 128 + c] = s ? 0x3F80u : 0u;
                if (s) v = 0.0;
            }
        }
        __syncthreads();   // LDS reused next site
    }
}

// ---------------- conv3x3 (+folded BN), barrier-free K-loop -------------------
// Block: 1 image, 128-pixel strip (4 rows) x 128 couts. The strip + halo
// (6 rows x 34 cols x 128 ch, swizzled) is staged into LDS ONCE; all 9 taps
// read shifted views. B-fragments load global->VGPR directly (L2-resident,
// pre-swizzled wp) - no barriers in the K-loop. Channel-group position is
// XOR-swizzled by (col&7) so pixel-major reads/writes are bank-conflict-free.
template<int NSPLIT, bool OUT_NCHW>
__global__ __launch_bounds__(256, 3)
void conv_kernel(const __bf16* __restrict__ sin, const __bf16* __restrict__ wp,
                 const float* __restrict__ off, float* __restrict__ out)
{
    __shared__ __bf16 img[6 * 34 * 128];   // 52,224 B
    const int tid  = threadIdx.x;
    const int blk  = blockIdx.x;
    const int tb   = blk >> 3;        // image index (t*32+b)
    const int pblk = blk & 7;         // 128-pixel strip (4 rows)
    const int wave = tid >> 6;
    const int wm = wave >> 1, wn = wave & 1;
    const int lane15 = tid & 15;
    const int q = (tid >> 4) & 3;

    // ---- stage strip + halo into LDS (halo zeroed), once ----
    const int y0 = pblk << 2;
    for (int unit = tid; unit < 3264; unit += 256) {     // 204 pixels x 16 groups
        const int sp = unit >> 4, G = unit & 15;
        const int row = sp / 34, col = sp - row * 34;
        const int y = y0 + row - 1, xg = col - 1;
        int4 v = {0, 0, 0, 0};
        if (y >= 0 && y < 32 && xg >= 0 && xg < 32)
            v = *(const int4*)(sin + (((size_t)tb * 1024 + y * 32 + xg) * 128 + G * 8));
        *(int4*)&img[sp * 128 + ((G ^ (col & 7)) * 8)] = v;
    }
    __syncthreads();

    f32x4 acc[4][4];
#pragma unroll
    for (int i = 0; i < 4; ++i)
#pragma unroll
        for (int j = 0; j < 4; ++j)
#pragma unroll
            for (int rg = 0; rg < 4; ++rg) acc[i][j][rg] = 0.0f;

    // per-i pixel coords within strip: pixel = wm*64 + i*16 + lane15
    int yi[4], xi[4];
#pragma unroll
    for (int i = 0; i < 4; ++i) {
        yi[i] = wm * 2 + (i >> 1);
        xi[i] = (i & 1) * 16 + lane15;
    }

    for (int tap = 0; tap < 9; ++tap) {
        const int dy = tap / 3 - 1;
        const int dx = tap - (tap / 3) * 3 - 1;
#pragma unroll
        for (int ci = 0; ci < 4; ++ci) {
            const int kc = tap * 4 + ci;
            bf16x8 af[4];
#pragma unroll
            for (int i = 0; i < 4; ++i) {
                const int col = xi[i] + 1 + dx;
                const int sp  = (yi[i] + 1 + dy) * 34 + col;
                const int g   = (ci * 4 + q) ^ (col & 7);
                af[i] = *(const bf16x8*)&img[sp * 128 + g * 8];
            }
#pragma unroll
            for (int s = 0; s < NSPLIT; ++s) {
#pragma unroll
                for (int j = 0; j < 4; ++j) {
                    const bf16x8 bf = *(const bf16x8*)(wp +
                        (((size_t)(s * 36 + kc) * 128 + wn * 64 + j * 16 + lane15) * 32 + q * 8));
#pragma unroll
                    for (int i = 0; i < 4; ++i)
                        acc[i][j] = __builtin_amdgcn_mfma_f32_16x16x32_bf16(af[i], bf, acc[i][j], 0, 0, 0);
                }
            }
        }
    }

    // epilogue: + BN offset, store (C/D map: col=lane&15, row=quad*4+reg)
    float offv[4];
#pragma unroll
    for (int j = 0; j < 4; ++j) offv[j] = off[wn * 64 + j * 16 + lane15];
#pragma unroll
    for (int i = 0; i < 4; ++i) {
        const int prow = pblk * 128 + wm * 64 + i * 16 + q * 4;
#pragma unroll
        for (int j = 0; j < 4; ++j) {
            const int col = wn * 64 + j * 16 + lane15;
            if (OUT_NCHW) {
                f32x4 vv;
#pragma unroll
                for (int rg = 0; rg < 4; ++rg) vv[rg] = acc[i][j][rg] + offv[j];
                *(f32x4*)&out[(size_t)tb * 131072 + (size_t)col * 1024 + prow] = vv;
            } else {
#pragma unroll
                for (int rg = 0; rg < 4; ++rg)
                    out[((size_t)tb * 1024 + prow + rg) * 128 + col] = acc[i][j][rg] + offv[j];
            }
        }
    }
}

extern "C" void kernel_launch(void* const* d_in, const int* in_sizes, int n_in,
                              void* d_out, int out_size, void* d_ws, size_t ws_size,
                              hipStream_t stream)
{
    const float* x  = (const float*)d_in[0];
    const float* w1 = (const float*)d_in[1];
    const float* g1 = (const float*)d_in[2];
    const float* b1 = (const float*)d_in[3];
    const float* m1 = (const float*)d_in[4];
    const float* v1 = (const float*)d_in[5];
    const float* w2 = (const float*)d_in[6];
    const float* g2 = (const float*)d_in[7];
    const float* b2 = (const float*)d_in[8];
    const float* m2 = (const float*)d_in[9];
    const float* v2 = (const float*)d_in[10];
    float* out = (float*)d_out;

    // ws layout: spikes (bf16, s1 then s2 reuse) | y1 f32 | weights | off | cnt | list
    char* ws = (char*)d_ws;
    __bf16* s_buf = (__bf16*)ws;                                       // 67,108,864 B
    float*  y1    = (float*)(ws + (size_t)67108864);                   // 134,217,728 B
    __bf16* wp    = (__bf16*)(ws + (size_t)201326592);                 // 1,474,560 B
    float*  off   = (float*)(ws + (size_t)202801152);                  // 1,024 B
    int*    cnt   = (int*)  (ws + (size_t)202802176);                  // 4 B
    int*    list  = (int*)  (ws + (size_t)202802180);                  // 16 MB cap

    prep_kernel<<<1152, 256, 0, stream>>>(w1, g1, b1, m1, v1, w2, g2, b2, m2, v2, wp, off, cnt);
    if1_kernel<<<1024, 256, 0, stream>>>(x, s_buf);
    conv_kernel<3, false><<<2048, 256, 0, stream>>>(s_buf, wp, off, y1);
    if2_kernel<<<4096, 256, 0, stream>>>(y1, s_buf, cnt, list);
    redo_kernel<<<2048, 256, 0, stream>>>(x, w1, g1, b1, m1, v1, cnt, list, s_buf);
    conv_kernel<2, true><<<2048, 256, 0, stream>>>(s_buf, wp + 442368, off + 128, out);
}

// Round 5
// 644.873 us; speedup vs baseline: 8.7557x; 1.4893x over previous
//
#include <hip/hip_runtime.h>
#include <hip/hip_bf16.h>

typedef __bf16 bf16x8 __attribute__((ext_vector_type(8)));
typedef float  f32x4  __attribute__((ext_vector_type(4)));

#define DELTA 5e-5f
#define LIST_CAP 4194304

// ---------------- weight prep: fold BN scale, split bf16, swizzle --------------
// conv1: 3 splits (hi/mid/lo), conv2: 2 splits. Layout per conv:
//   wp[split][kc][cout][32], k = r*128+cin, kc=k>>5, split stride 147456.
__global__ void prep_kernel(const float* __restrict__ w1, const float* __restrict__ g1,
                            const float* __restrict__ b1, const float* __restrict__ m1,
                            const float* __restrict__ v1,
                            const float* __restrict__ w2, const float* __restrict__ g2,
                            const float* __restrict__ b2, const float* __restrict__ m2,
                            const float* __restrict__ v2,
                            __bf16* __restrict__ wp, float* __restrict__ off,
                            int* __restrict__ cnt)
{
    int idx  = blockIdx.x * 256 + threadIdx.x;     // 0 .. 294911
    if (idx == 0) cnt[0] = 0;                      // ws is re-poisoned every launch
    int conv = idx / 147456;
    int rem  = idx - conv * 147456;
    int cout = rem / 1152;
    int k    = rem - cout * 1152;                  // k = r*128 + cin
    int r    = k >> 7;
    int cin  = k & 127;
    const float* w  = conv ? w2 : w1;
    const float* g  = conv ? g2 : g1;
    const float* vr = conv ? v2 : v1;
    float inv = g[cout] / sqrtf(vr[cout] + 1e-5f);
    float wv  = w[(cout * 128 + cin) * 9 + r] * inv;
    int kc = k >> 5, kk = k & 31;
    size_t pos = ((size_t)kc * 128 + cout) * 32 + kk;
    if (conv == 0) {
        __bf16 s0 = (__bf16)wv;
        float r1 = wv - (float)s0;
        __bf16 s1 = (__bf16)r1;
        __bf16 s2 = (__bf16)(r1 - (float)s1);
        wp[pos]              = s0;
        wp[147456 + pos]     = s1;
        wp[294912 + pos]     = s2;
    } else {
        __bf16 hi = (__bf16)wv;
        __bf16 lo = (__bf16)(wv - (float)hi);
        wp[442368 + pos]          = hi;
        wp[442368 + 147456 + pos] = lo;
    }
    if (idx < 256) {
        int cv = idx >> 7, co = idx & 127;
        const float* gg = cv ? g2 : g1;
        const float* bb = cv ? b2 : b1;
        const float* mm = cv ? m2 : m1;
        const float* vx = cv ? v2 : v1;
        float iv = gg[co] / sqrtf(vx[co] + 1e-5f);
        off[cv * 128 + co] = bb[co] - mm[co] * iv;
    }
}

// ---------------- IF neuron #1: x [T,B,C,H,W] f32 -> spikes NHWC bf16 ----------
// fp64 membrane: bit-matches an fp64 reference's spike decisions.
__global__ void if1_kernel(const float* __restrict__ x, __bf16* __restrict__ s1)
{
    const int blk = blockIdx.x;        // 1024 = B*H
    const int b   = blk >> 5;
    const int h   = blk & 31;
    const int tid = threadIdx.x;
    const int w   = tid & 31;
    const int g   = tid >> 5;          // 8 groups of 16 channels
    double v[16];
#pragma unroll
    for (int i = 0; i < 16; ++i) v[i] = 0.0;
    for (int t = 0; t < 8; ++t) {
        const size_t xbase = ((((size_t)t * 32 + b) * 128 + g * 16) * 32 + h) * 32 + w;
        unsigned short sp[16];
#pragma unroll
        for (int i = 0; i < 16; ++i) {
            v[i] += (double)x[xbase + (size_t)i * 1024];
            const bool s = (v[i] >= 1.0);
            sp[i] = s ? 0x3F80u : 0u;   // bf16 1.0 / 0.0
            if (s) v[i] = 0.0;
        }
        const size_t obase = (((size_t)(t * 32 + b) * 1024 + h * 32 + w) * 128 + g * 16);
        *(int4*)((unsigned short*)s1 + obase)     = *(const int4*)&sp[0];
        *(int4*)((unsigned short*)s1 + obase + 8) = *(const int4*)&sp[8];
    }
}

// ---------------- IF neuron #2 phase A: scan + flag near-threshold sites ------
__global__ void if2_kernel(const float* __restrict__ y1, __bf16* __restrict__ s2,
                           int* __restrict__ cnt, int* __restrict__ list)
{
    const size_t idx = (size_t)blockIdx.x * 256 + threadIdx.x;  // 1,048,576 threads
    const int c4 = (int)(idx & 31);
    const int p  = (int)((idx >> 5) & 1023);
    const int b  = (int)(idx >> 15);
    float v[4];
    int flag = 0;
#pragma unroll
    for (int i = 0; i < 4; ++i) v[i] = 0.f;
    for (int t = 0; t < 8; ++t) {
        const size_t base = ((size_t)(t * 32 + b) * 1024 + p) * 128 + c4 * 4;
        const f32x4 xv = *(const f32x4*)&y1[base];
        unsigned short sp[4];
#pragma unroll
        for (int i = 0; i < 4; ++i) {
            v[i] += xv[i];
            const float d = v[i] - 1.0f;
            if (fabsf(d) < DELTA) flag |= (1 << i);
            const bool s = (d >= 0.0f);
            sp[i] = s ? 0x3F80u : 0u;
            if (s) v[i] = 0.f;
        }
        *(uint2*)((unsigned short*)s2 + base) = *(const uint2*)&sp[0];
    }
    if (flag) {
#pragma unroll 1
        for (int i = 0; i < 4; ++i)
            if ((flag >> i) & 1) {
                const int pos = atomicAdd(cnt, 1);
                if (pos < LIST_CAP)
                    list[pos] = (b << 17) | (p << 7) | (c4 * 4 + i);
            }
    }
}

// ---------------- IF#2 phase B: fp64 redo, one 256-thread block per site ------
__global__ __launch_bounds__(256)
void redo_kernel(const float* __restrict__ x, const float* __restrict__ w1,
                 const float* __restrict__ g1, const float* __restrict__ b1,
                 const float* __restrict__ m1, const float* __restrict__ v1r,
                 const int* __restrict__ cnt, const int* __restrict__ list,
                 __bf16* __restrict__ s2)
{
    __shared__ double red[256][8];   // 16 KB
    const int count = min(cnt[0], LIST_CAP);
    const int tid = threadIdx.x;
    const int cin = tid & 127;
    const int tg  = tid >> 7;
    for (int i = blockIdx.x; i < count; i += gridDim.x) {
        const int pk = list[i];
        const int b = pk >> 17, p = (pk >> 7) & 1023, c = pk & 127;
        const int h = p >> 5, w_ = p & 31;
        double part[8];
#pragma unroll
        for (int t = 0; t < 8; ++t) part[t] = 0.0;
        const int tap0 = tg ? 5 : 0, tap1 = tg ? 9 : 5;
        for (int tap = tap0; tap < tap1; ++tap) {
            const int hh = h + tap / 3 - 1;
            const int ww = w_ + tap - (tap / 3) * 3 - 1;
            if (hh < 0 || hh > 31 || ww < 0 || ww > 31) continue;
            const int pix = hh * 32 + ww;
            const double wv = (double)w1[(size_t)(c * 128 + cin) * 9 + tap];
            double v = 0.0;
#pragma unroll
            for (int t = 0; t < 8; ++t) {
                v += (double)x[((size_t)(t * 32 + b) * 128 + cin) * 1024 + pix];
                if (v >= 1.0) { part[t] += wv; v = 0.0; }
            }
        }
#pragma unroll
        for (int t = 0; t < 8; ++t) red[tid][t] = part[t];
        __syncthreads();
        for (int s = 128; s > 0; s >>= 1) {
            if (tid < s)
#pragma unroll
                for (int t = 0; t < 8; ++t) red[tid][t] += red[tid + s][t];
            __syncthreads();
        }
        if (tid == 0) {
            const double inv  = (double)g1[c] / sqrt((double)v1r[c] + 1e-5);
            const double offc = (double)b1[c] - (double)m1[c] * inv;
            double v = 0.0;
#pragma unroll
            for (int t = 0; t < 8; ++t) {
                v += red[0][t] * inv + offc;
                const bool s = (v >= 1.0);
                ((unsigned short*)s2)[((size_t)(t * 32 + b) * 1024 + p) * 128 + c] = s ? 0x3F80u : 0u;
                if (s) v = 0.0;
            }
        }
        __syncthreads();   // LDS reused next site
    }
}

// ---------------- conv3x3 (+folded BN), barrier-free, B double-buffered -------
// Block: 1 image, 128-pixel strip (4 rows) x 128 couts. Strip+halo staged in
// LDS once (XOR-swizzled). Wave tile = 128 pixels x 32 couts: each B-fragment
// feeds 8 MFMAs; B-frags are double-buffered in registers with one-kc
// lookahead (prefetch covers L2 latency under the MFMA burst).
template<int NSPLIT, bool OUT_NCHW>
__global__ __launch_bounds__(256, 3)
void conv_kernel(const __bf16* __restrict__ sin, const __bf16* __restrict__ wp,
                 const float* __restrict__ off, float* __restrict__ out)
{
    __shared__ __bf16 img[6 * 34 * 128];   // 52,224 B
    const int tid  = threadIdx.x;
    const int blk  = blockIdx.x;
    const int tb   = blk >> 3;        // image index (t*32+b)
    const int pblk = blk & 7;         // 128-pixel strip (4 rows)
    const int wn   = tid >> 6;        // wave = cout quarter
    const int lane15 = tid & 15;
    const int q = (tid >> 4) & 3;

    // ---- stage strip + halo into LDS (halo zeroed), once ----
    const int y0 = pblk << 2;
    for (int unit = tid; unit < 3264; unit += 256) {     // 204 pixels x 16 groups
        const int sp = unit >> 4, G = unit & 15;
        const int row = sp / 34, col = sp - row * 34;
        const int y = y0 + row - 1, xg = col - 1;
        int4 v = {0, 0, 0, 0};
        if (y >= 0 && y < 32 && xg >= 0 && xg < 32)
            v = *(const int4*)(sin + (((size_t)tb * 1024 + y * 32 + xg) * 128 + G * 8));
        *(int4*)&img[sp * 128 + ((G ^ (col & 7)) * 8)] = v;
    }
    __syncthreads();

    f32x4 acc[8][2];
#pragma unroll
    for (int i = 0; i < 8; ++i)
#pragma unroll
        for (int j = 0; j < 2; ++j)
#pragma unroll
            for (int rg = 0; rg < 4; ++rg) acc[i][j][rg] = 0.0f;

    // B fragment loader: wave-coalesced 1KB (16 couts x 32 k) per (s,j)
    const __bf16* wbase = wp + ((size_t)(wn * 32 + lane15) * 32 + q * 8);
#define BLOAD(s, j, kc) (*(const bf16x8*)(wbase + ((size_t)((s) * 36 + (kc)) * 128 + (j) * 16) * 32))

    bf16x8 buf[2][NSPLIT][2];
#pragma unroll
    for (int s = 0; s < NSPLIT; ++s)
#pragma unroll
        for (int j = 0; j < 2; ++j) buf[0][s][j] = BLOAD(s, j, 0);

    for (int tap = 0; tap < 9; ++tap) {
        const int dy = tap / 3 - 1;
        const int dx = tap - (tap / 3) * 3 - 1;
#pragma unroll
        for (int ci = 0; ci < 4; ++ci) {
            const int kc = tap * 4 + ci;
            // prefetch next kc's B into the other buffer (kc=35: dummy, unused)
            const int kcn = kc < 35 ? kc + 1 : 35;
#pragma unroll
            for (int s = 0; s < NSPLIT; ++s)
#pragma unroll
                for (int j = 0; j < 2; ++j)
                    buf[(ci + 1) & 1][s][j] = BLOAD(s, j, kcn);
#pragma unroll
            for (int ih = 0; ih < 2; ++ih) {
                bf16x8 af[4];
#pragma unroll
                for (int i4 = 0; i4 < 4; ++i4) {
                    const int i = ih * 4 + i4;
                    const int col = (i & 1) * 16 + lane15 + 1 + dx;
                    const int sp  = ((i >> 1) + 1 + dy) * 34 + col;
                    const int g   = (ci * 4 + q) ^ (col & 7);
                    af[i4] = *(const bf16x8*)&img[sp * 128 + g * 8];
                }
#pragma unroll
                for (int s = 0; s < NSPLIT; ++s)
#pragma unroll
                    for (int j = 0; j < 2; ++j)
#pragma unroll
                        for (int i4 = 0; i4 < 4; ++i4)
                            acc[ih * 4 + i4][j] = __builtin_amdgcn_mfma_f32_16x16x32_bf16(
                                af[i4], buf[ci & 1][s][j], acc[ih * 4 + i4][j], 0, 0, 0);
            }
        }
    }
#undef BLOAD

    // epilogue: + BN offset, store (C/D map: col=lane&15, row=quad*4+reg)
    float offv[2];
#pragma unroll
    for (int j = 0; j < 2; ++j) offv[j] = off[wn * 32 + j * 16 + lane15];
#pragma unroll
    for (int i = 0; i < 8; ++i) {
        const int prow = pblk * 128 + i * 16 + q * 4;
#pragma unroll
        for (int j = 0; j < 2; ++j) {
            const int col = wn * 32 + j * 16 + lane15;
            if (OUT_NCHW) {
                f32x4 vv;
#pragma unroll
                for (int rg = 0; rg < 4; ++rg) vv[rg] = acc[i][j][rg] + offv[j];
                *(f32x4*)&out[(size_t)tb * 131072 + (size_t)col * 1024 + prow] = vv;
            } else {
#pragma unroll
                for (int rg = 0; rg < 4; ++rg)
                    out[((size_t)tb * 1024 + prow + rg) * 128 + col] = acc[i][j][rg] + offv[j];
            }
        }
    }
}

extern "C" void kernel_launch(void* const* d_in, const int* in_sizes, int n_in,
                              void* d_out, int out_size, void* d_ws, size_t ws_size,
                              hipStream_t stream)
{
    const float* x  = (const float*)d_in[0];
    const float* w1 = (const float*)d_in[1];
    const float* g1 = (const float*)d_in[2];
    const float* b1 = (const float*)d_in[3];
    const float* m1 = (const float*)d_in[4];
    const float* v1 = (const float*)d_in[5];
    const float* w2 = (const float*)d_in[6];
    const float* g2 = (const float*)d_in[7];
    const float* b2 = (const float*)d_in[8];
    const float* m2 = (const float*)d_in[9];
    const float* v2 = (const float*)d_in[10];
    float* out = (float*)d_out;

    // ws layout: spikes (bf16, s1 then s2 reuse) | y1 f32 | weights | off | cnt | list
    char* ws = (char*)d_ws;
    __bf16* s_buf = (__bf16*)ws;                                       // 67,108,864 B
    float*  y1    = (float*)(ws + (size_t)67108864);                   // 134,217,728 B
    __bf16* wp    = (__bf16*)(ws + (size_t)201326592);                 // 1,474,560 B
    float*  off   = (float*)(ws + (size_t)202801152);                  // 1,024 B
    int*    cnt   = (int*)  (ws + (size_t)202802176);                  // 4 B
    int*    list  = (int*)  (ws + (size_t)202802180);                  // 16 MB cap

    prep_kernel<<<1152, 256, 0, stream>>>(w1, g1, b1, m1, v1, w2, g2, b2, m2, v2, wp, off, cnt);
    if1_kernel<<<1024, 256, 0, stream>>>(x, s_buf);
    conv_kernel<3, false><<<2048, 256, 0, stream>>>(s_buf, wp, off, y1);
    if2_kernel<<<4096, 256, 0, stream>>>(y1, s_buf, cnt, list);
    redo_kernel<<<2048, 256, 0, stream>>>(x, w1, g1, b1, m1, v1, cnt, list, s_buf);
    conv_kernel<2, true><<<2048, 256, 0, stream>>>(s_buf, wp + 442368, off + 128, out);
}